// Round 15
// baseline (492.905 us; speedup 1.0000x reference)
//
#include <hip/hip_runtime.h>
#include <hip/hip_bf16.h>
#include <hip/hip_fp16.h>

// LightGCN 3-hop propagation, 150k nodes, 4.8M edges, EMB=64.
// Round 20 (session R14):
//  - bin + local_fill: rank-capture trick. The FIRST LDS atomicAdd returns
//    each edge's rank within its bucket/row; position = excl[b] + rank after
//    the scan -> second atomic pass ELIMINATED (9.6M -> 4.8M LDS atomics in
//    bin; scatter in local_fill now atomic-free). local_fill's LDS stage
//    dropped (R14 proved it null): <=9 records/thread held in registers
//    (static unroll, CAP/1024 = 9).
//  - hop UNTOUCHED (structural: R8 concurrency null, R9/R10 width saturated,
//    R13 VALU null; 94us = 298MB random L3 fetches).
// R17: 1024-thr local_fill + in-block base reduce. R16: fixed-cap buckets.
// R15: uint4 gathers. R11: depth-2 pipeline. R9: fp16 internal storage.

#define NUM_USERS 100000
#define NUM_ITEMS 50000
#define N_NODES   150000
#define EMB       64
#define N_EDGES   4800000
#define NODE_ELEMS (N_NODES * EMB)   // 9,600,000
#define U_ELEMS    (NUM_USERS * EMB) // 6,400,000
#define I_ELEMS    (NUM_ITEMS * EMB) // 3,200,000

#define RPB 256                       // rows per bucket (2^8: row>>8, row&255)
#define NB  ((N_NODES + RPB - 1) / RPB)   // 586 buckets
#define CAP 9216                      // bucket capacity (mean 8192, sigma~90)
#define LFI (CAP / 1024)              // local_fill records per thread (9)
#define EPB 4096                      // edges staged per bin block
#define EPW (EPB / 1024)              // edges per thread in bin_kernel

typedef __hip_bfloat16 bf16;
typedef float v2f __attribute__((ext_vector_type(2)));

__device__ __forceinline__ unsigned int pack_bf16(float a, float b) {
    bf16 x = __float2bfloat16(a), y = __float2bfloat16(b);
    return ((unsigned int)(*reinterpret_cast<unsigned short*>(&y)) << 16) |
           (*reinterpret_cast<unsigned short*>(&x));
}
__device__ __forceinline__ float bf_lo(unsigned int u) { return __uint_as_float(u << 16); }
__device__ __forceinline__ float bf_hi(unsigned int u) { return __uint_as_float(u & 0xffff0000u); }
__device__ __forceinline__ float2 h2f(unsigned int u) {
    return __half22float2(*reinterpret_cast<const __half2*>(&u));
}

// flag bit0: float arrays are bf16 (else fp32). bit1: edge_index int64 (else int32).
__global__ void detect_kernel(const unsigned short* __restrict__ u16,
                              const int* __restrict__ ei32,
                              int* __restrict__ flag,
                              int* __restrict__ bucket_off)
{
    __shared__ int s_fp32, s_i32;
    if (threadIdx.x == 0) { s_fp32 = 0; s_i32 = 0; }
    __syncthreads();
    int t = threadIdx.x;
    for (int i = t; i < NB + 1; i += 256) bucket_off[i] = i * CAP;
    unsigned short u = u16[t];
    int e = (u >> 7) & 0xFF;
    if (e >= 0xC0) atomicOr(&s_fp32, 1);
    if (t < 64 && ei32[2 * t + 1] != 0) atomicOr(&s_i32, 1);
    __syncthreads();
    if (t == 0) {
        int f = 0;
        if (!s_fp32) f |= 1;
        if (!s_i32)  f |= 2;
        *flag = f;
    }
}

__device__ __forceinline__ int load_row(const int* ei32, int f, size_t e) {
    return (f & 2) ? ei32[2 * e] : ei32[e];
}
__device__ __forceinline__ int load_col(const int* ei32, int f, size_t e) {
    return (f & 2) ? ei32[2 * ((size_t)N_EDGES + e)] : ei32[(size_t)N_EDGES + e];
}
__device__ __forceinline__ float load_w(const void* ew, int f, size_t e) {
    return (f & 1) ? __bfloat162float(((const bf16*)ew)[e]) : ((const float*)ew)[e];
}

// ---------- vectorized init: A (16-bit packed) + passthrough ----------
__global__ void init_vec_kernel(const void* __restrict__ users,
                                const void* __restrict__ items,
                                void* __restrict__ out,
                                void* __restrict__ A,
                                const int* __restrict__ flag)
{
    int g = blockIdx.x * blockDim.x + threadIdx.x;   // NODE_ELEMS/4 threads
    if (g >= NODE_ELEMS / 4) return;
    int g4 = g * 4;
    const bool isb = ((*flag) & 1);
    if (isb) {
        uint2 v;
        if (g4 < U_ELEMS) {
            v = ((const uint2*)users)[g];
            ((uint2*)((bf16*)out + U_ELEMS))[g] = v;
        } else {
            int ii = g - U_ELEMS / 4;
            v = ((const uint2*)items)[ii];
            ((uint2*)((bf16*)out + 2 * (size_t)U_ELEMS + I_ELEMS))[ii] = v;
        }
        ((uint2*)A)[g] = v;            // A stored bf16
    } else {
        float4 v;
        if (g4 < U_ELEMS) {
            v = ((const float4*)users)[g];
            ((float4*)((float*)out + U_ELEMS))[g] = v;
        } else {
            int ii = g - U_ELEMS / 4;
            v = ((const float4*)items)[ii];
            ((float4*)((float*)out + 2 * (size_t)U_ELEMS + I_ELEMS))[ii] = v;
        }
        __half2 ha = __floats2half2_rn(v.x, v.y);
        __half2 hb = __floats2half2_rn(v.z, v.w);
        uint2 u2;
        u2.x = *reinterpret_cast<unsigned int*>(&ha);
        u2.y = *reinterpret_cast<unsigned int*>(&hb);
        ((uint2*)A)[g] = u2;           // A stored fp16 (intermediates 16-bit)
    }
}

// ---------- binned CSR build (fixed-capacity buckets) ----------

// stage EPB edges in LDS, rank by bucket (rank-capture: ONE atomic/edge),
// append bucket-contiguous runs into fixed-cap rec regions [b*CAP,(b+1)*CAP).
__global__ __launch_bounds__(1024) void bin_kernel(const int* __restrict__ ei32,
                                                   const void* __restrict__ ew,
                                                   int* __restrict__ bucket_off,
                                                   int2* __restrict__ rec,
                                                   const int* __restrict__ flag)
{
    __shared__ int2 stage[EPB];            // 32 KB
    __shared__ unsigned short bof[EPB];    // 8 KB
    __shared__ int hist[NB], excl0[NB], gbase[NB];
    __shared__ int ls[16];
    const int t = threadIdx.x;
    const size_t base_e = (size_t)blockIdx.x * EPB;
    const int cnt = (int)(((base_e + EPB) <= N_EDGES) ? EPB : (N_EDGES - base_e));
    for (int i = t; i < NB; i += 1024) hist[i] = 0;
    __syncthreads();
    const int f = *flag;
    int  mybkt[EPW];
    int  myrk[EPW];
    int2 myrec[EPW];
    #pragma unroll
    for (int k = 0; k < EPW; ++k) {
        int idx = k * 1024 + t;
        if (idx < cnt) {
            size_t e = base_e + idx;
            int row, col;
            if (f & 2) {   // int64 input: int2 vector load, keep low word
                row = ((const int2*)ei32)[e].x;
                col = ((const int2*)ei32)[(size_t)N_EDGES + e].x;
            } else {
                row = ei32[e];
                col = ei32[(size_t)N_EDGES + e];
            }
            float w = load_w(ew, f, e);
            mybkt[k] = row >> 8;
            myrec[k] = make_int2(col | ((row & 255) << 18), __float_as_int(w));
            myrk[k]  = atomicAdd(&hist[mybkt[k]], 1);   // rank capture
        } else mybkt[k] = -1;
    }
    __syncthreads();
    {   // scan hist[0..NB) -> excl0
        const int lane = t & 63, wv = t >> 6;
        int x = (t < NB) ? hist[t] : 0;
        int v = x;
        #pragma unroll
        for (int d = 1; d < 64; d <<= 1) { int y = __shfl_up(v, d, 64); if (lane >= d) v += y; }
        if (lane == 63) ls[wv] = v;
        __syncthreads();
        if (wv == 0 && lane < 16) {
            int s = ls[lane];
            #pragma unroll
            for (int d = 1; d < 16; d <<= 1) { int y = __shfl_up(s, d, 64); if (lane >= d) s += y; }
            ls[lane] = s;
        }
        __syncthreads();
        int waveoff = wv ? ls[wv - 1] : 0;
        int excl = waveoff + v - x;
        if (t < NB) excl0[t] = excl;
    }
    __syncthreads();
    if (t < NB && hist[t] > 0) gbase[t] = atomicAdd(&bucket_off[t], hist[t]);
    else if (t < NB)           gbase[t] = 0;
    #pragma unroll
    for (int k = 0; k < EPW; ++k) {
        if (mybkt[k] >= 0) {
            int p = excl0[mybkt[k]] + myrk[k];    // no second atomic
            stage[p] = myrec[k];
            bof[p]   = (unsigned short)mybkt[k];
        }
    }
    __syncthreads();
    for (int s = t; s < cnt; s += 1024) {
        int b = bof[s];
        int pos = gbase[b] + (s - excl0[b]);
        if (pos < (b + 1) * CAP)           // overflow clamp (11-sigma margin)
            rec[pos] = stage[s];
    }
}

// one 1024-thread block per bucket: records held in REGISTERS (<=9/thread),
// rank-capture hist (one atomic/edge), scan -> rowptr, atomic-free scatter.
__global__ __launch_bounds__(1024) void local_fill_kernel(
                                  const int* __restrict__ bucket_off,
                                  const int2* __restrict__ rec,
                                  int2* __restrict__ csr,
                                  int* __restrict__ rowptr)
{
    __shared__ int hist[RPB], base_[RPB], ls[4], s_red[16], s_dlo;
    const int b = blockIdx.x, t = threadIdx.x;      // 1024 threads
    const int src = b * CAP;
    int cnt = bucket_off[b] - src;
    if (cnt > CAP) cnt = CAP;
    const int rows = (N_NODES - b * RPB < RPB) ? (N_NODES - b * RPB) : RPB;
    const int lane = t & 63, wv = t >> 6;

    // exclusive sum of bucket counts for i < b (dense csr base)
    int partial = 0;
    for (int i = t; i < b; i += 1024) {
        int c = bucket_off[i] - i * CAP;
        if (c > CAP) c = CAP;
        partial += c;
    }
    #pragma unroll
    for (int d = 1; d < 64; d <<= 1) partial += __shfl_xor(partial, d, 64);
    if (lane == 0) s_red[wv] = partial;
    if (t < RPB) hist[t] = 0;
    __syncthreads();
    if (t == 0) {
        int s = 0;
        #pragma unroll
        for (int i = 0; i < 16; ++i) s += s_red[i];
        s_dlo = s;
    }
    // load + rank-capture (static unroll -> registers, not scratch)
    int2 myr[LFI];
    int  myrk[LFI];
    #pragma unroll
    for (int j = 0; j < LFI; ++j) {
        int s = t + j * 1024;
        if (s < cnt) {
            int2 r = rec[src + s];
            myr[j]  = r;
            myrk[j] = atomicAdd(&hist[r.x >> 18], 1);
        } else myrk[j] = -1;
    }
    __syncthreads();
    const int dlo = s_dlo;
    int x = (t < RPB) ? hist[t] : 0;
    int v = x;
    #pragma unroll
    for (int d = 1; d < 64; d <<= 1) { int y = __shfl_up(v, d, 64); if (lane >= d) v += y; }
    if (t < RPB && lane == 63) ls[wv] = v;
    __syncthreads();
    if (wv == 0 && lane < 4) {
        int s = ls[lane];
        #pragma unroll
        for (int d = 1; d < 4; d <<= 1) { int y = __shfl_up(s, d, 64); if (lane >= d) s += y; }
        ls[lane] = s;
    }
    __syncthreads();
    if (t < RPB) {
        int waveoff = wv ? ls[wv - 1] : 0;
        int excl = waveoff + v - x;
        if (t < rows) rowptr[b * RPB + t] = dlo + excl;
        base_[t] = dlo + excl;
    }
    if (b == NB - 1 && t == 0) rowptr[N_NODES] = dlo + cnt;
    __syncthreads();
    #pragma unroll
    for (int j = 0; j < LFI; ++j) {
        if (myrk[j] >= 0) {
            int rl = myr[j].x >> 18;
            int pos = base_[rl] + myrk[j];        // atomic-free scatter
            csr[pos] = make_int2(myr[j].x & 0x3FFFF, myr[j].y);
        }
    }
}

// ---------- gather hop core: uint4 gathers, packed-fp32 FMA ----------
// Lane q=(tid>>3)&7 owns edge-slot q of each 8-edge step; hl=tid&7 owns
// dims {8hl..8hl+7} as one uint4 (8 x 16-bit). 16-edge chunk = 2 steps.
// Accumulate in 4x float2 via __builtin_elementwise_fma -> v_pk_fma_f32.
// Main loop: depth-2 pipeline. Tail: ONE predicated 16-slot step.

template <bool ISB>
__device__ __forceinline__ void gather_row8(const int2* __restrict__ csr,
                                            const uint4* __restrict__ p,
                                            int s, int e, int q, int hl,
                                            float f[8])
{
    const int len   = e - s;
    const int nfull = len >> 4;          // full 16-edge chunks
    const int rem   = len & 15;

    v2f a01 = {0.f, 0.f}, a23 = {0.f, 0.f}, a45 = {0.f, 0.f}, a67 = {0.f, 0.f};

    int2 cwA[2], cwB[2];
    uint4 vA[2], vB[2];

#define LD_CSR(cw, base)                                             \
    _Pragma("unroll")                                                \
    for (int u = 0; u < 2; ++u) (cw)[u] = csr[(base) + 8 * u + q];
#define GATHER(v, cw)                                                \
    _Pragma("unroll")                                                \
    for (int u = 0; u < 2; ++u)                                      \
        (v)[u] = p[(size_t)((unsigned int)(cw)[u].x * 8u + hl)];
#define FMA2(cw, v)                                                  \
    _Pragma("unroll")                                                \
    for (int u = 0; u < 2; ++u) {                                    \
        float w = __int_as_float((cw)[u].y);                         \
        v2f wv = {w, w};                                             \
        v2f p01, p23, p45, p67;                                      \
        if (ISB) {                                                   \
            p01 = (v2f){bf_lo((v)[u].x), bf_hi((v)[u].x)};           \
            p23 = (v2f){bf_lo((v)[u].y), bf_hi((v)[u].y)};           \
            p45 = (v2f){bf_lo((v)[u].z), bf_hi((v)[u].z)};           \
            p67 = (v2f){bf_lo((v)[u].w), bf_hi((v)[u].w)};           \
        } else {                                                     \
            float2 fa = h2f((v)[u].x), fb = h2f((v)[u].y);           \
            float2 fc = h2f((v)[u].z), fd = h2f((v)[u].w);           \
            p01 = (v2f){fa.x, fa.y}; p23 = (v2f){fb.x, fb.y};        \
            p45 = (v2f){fc.x, fc.y}; p67 = (v2f){fd.x, fd.y};        \
        }                                                            \
        a01 = __builtin_elementwise_fma(wv, p01, a01);               \
        a23 = __builtin_elementwise_fma(wv, p23, a23);               \
        a45 = __builtin_elementwise_fma(wv, p45, a45);               \
        a67 = __builtin_elementwise_fma(wv, p67, a67);               \
    }

    if (nfull > 0) {
        LD_CSR(cwA, s);
        if (nfull > 1) LD_CSR(cwB, s + 16);
        GATHER(vA, cwA);
        int c = 0;
        while (true) {
            // chunk c in A, chunk c+1 in B
            if (c + 1 < nfull) GATHER(vB, cwB);
            FMA2(cwA, vA);
            if (c + 1 >= nfull) break;
            if (c + 2 < nfull) LD_CSR(cwA, s + (c + 2) * 16);
            ++c;
            // chunk c in B, chunk c+1 in A
            if (c + 1 < nfull) GATHER(vA, cwA);
            FMA2(cwB, vB);
            if (c + 1 >= nfull) break;
            if (c + 2 < nfull) LD_CSR(cwB, s + (c + 2) * 16);
            ++c;
        }
    }
    if (rem) {
        const int base = s + nfull * 16;
        int2 cw[2];
        #pragma unroll
        for (int u = 0; u < 2; ++u) {
            int idx = base + 8 * u + q;
            int j = (idx < e) ? idx : (e - 1);
            cw[u] = csr[j];
            if (idx >= e) cw[u].y = 0;     // w = 0 for padding slots
        }
        uint4 v[2];
        #pragma unroll
        for (int u = 0; u < 2; ++u)
            v[u] = p[(size_t)((unsigned int)cw[u].x * 8u + hl)];
        FMA2(cw, v);
    }
#undef LD_CSR
#undef GATHER
#undef FMA2
    f[0] = a01.x; f[1] = a01.y; f[2] = a23.x; f[3] = a23.y;
    f[4] = a45.x; f[5] = a45.y; f[6] = a67.x; f[7] = a67.y;
}

// LAST fuses epilogue: out = (emb0 + h1 + h2 + h3)/4.
template <bool LAST>
__global__ void hop_kernel(const int* __restrict__ rowptr,
                           const int2* __restrict__ csr,
                           const void* __restrict__ prev,
                           void* __restrict__ next,
                           const void* __restrict__ E0,   // emb0 (LAST only)
                           const void* __restrict__ H1,   // h1   (LAST only)
                           void* __restrict__ out,
                           const int* __restrict__ flag)
{
    int row = blockIdx.x * (blockDim.x >> 6) + (threadIdx.x >> 6);
    if (row >= N_NODES) return;
    const int q  = (threadIdx.x >> 3) & 7;
    const int hl = threadIdx.x & 7;
    const bool isb = ((*flag) & 1);
    const int s = rowptr[row], e = rowptr[row + 1];
    const uint4* p = (const uint4*)prev;
    float f[8] = {0.f, 0.f, 0.f, 0.f, 0.f, 0.f, 0.f, 0.f};
    if (isb) gather_row8<true >(csr, p, s, e, q, hl, f);
    else     gather_row8<false>(csr, p, s, e, q, hl, f);
    #pragma unroll
    for (int k = 0; k < 8; ++k) {        // combine the 8 edge-slot groups
        f[k] += __shfl_xor(f[k], 8);
        f[k] += __shfl_xor(f[k], 16);
        f[k] += __shfl_xor(f[k], 32);
    }
    if ((threadIdx.x & 56) != 0) return; // slot-0 lanes (8 per row) write
    size_t o16 = (size_t)row * 8 + hl;   // 8-element (16-byte) units
    if (LAST) {
        uint4 e0u = ((const uint4*)E0)[o16];
        uint4 h1u = ((const uint4*)H1)[o16];
        uint4 h2u = ((const uint4*)prev)[o16];
        float v[8];
        if (isb) {
            v[0] = (bf_lo(e0u.x) + bf_lo(h1u.x) + bf_lo(h2u.x) + f[0]) * 0.25f;
            v[1] = (bf_hi(e0u.x) + bf_hi(h1u.x) + bf_hi(h2u.x) + f[1]) * 0.25f;
            v[2] = (bf_lo(e0u.y) + bf_lo(h1u.y) + bf_lo(h2u.y) + f[2]) * 0.25f;
            v[3] = (bf_hi(e0u.y) + bf_hi(h1u.y) + bf_hi(h2u.y) + f[3]) * 0.25f;
            v[4] = (bf_lo(e0u.z) + bf_lo(h1u.z) + bf_lo(h2u.z) + f[4]) * 0.25f;
            v[5] = (bf_hi(e0u.z) + bf_hi(h1u.z) + bf_hi(h2u.z) + f[5]) * 0.25f;
            v[6] = (bf_lo(e0u.w) + bf_lo(h1u.w) + bf_lo(h2u.w) + f[6]) * 0.25f;
            v[7] = (bf_hi(e0u.w) + bf_hi(h1u.w) + bf_hi(h2u.w) + f[7]) * 0.25f;
            uint4 o;
            o.x = pack_bf16(v[0], v[1]);
            o.y = pack_bf16(v[2], v[3]);
            o.z = pack_bf16(v[4], v[5]);
            o.w = pack_bf16(v[6], v[7]);
            size_t oo = o16 + ((row < NUM_USERS) ? 0 : (size_t)(U_ELEMS / 8));
            ((uint4*)out)[oo] = o;
        } else {
            float2 a0 = h2f(e0u.x), a1 = h2f(e0u.y), a2 = h2f(e0u.z), a3 = h2f(e0u.w);
            float2 b0 = h2f(h1u.x), b1 = h2f(h1u.y), b2 = h2f(h1u.z), b3 = h2f(h1u.w);
            float2 c0 = h2f(h2u.x), c1 = h2f(h2u.y), c2 = h2f(h2u.z), c3 = h2f(h2u.w);
            v[0] = (a0.x + b0.x + c0.x + f[0]) * 0.25f;
            v[1] = (a0.y + b0.y + c0.y + f[1]) * 0.25f;
            v[2] = (a1.x + b1.x + c1.x + f[2]) * 0.25f;
            v[3] = (a1.y + b1.y + c1.y + f[3]) * 0.25f;
            v[4] = (a2.x + b2.x + c2.x + f[4]) * 0.25f;
            v[5] = (a2.y + b2.y + c2.y + f[5]) * 0.25f;
            v[6] = (a3.x + b3.x + c3.x + f[6]) * 0.25f;
            v[7] = (a3.y + b3.y + c3.y + f[7]) * 0.25f;
            size_t fo = (size_t)row * 64 + (size_t)hl * 8 +
                        ((row < NUM_USERS) ? 0 : (size_t)U_ELEMS);
            float4* op = (float4*)((float*)out + fo);
            op[0] = make_float4(v[0], v[1], v[2], v[3]);
            op[1] = make_float4(v[4], v[5], v[6], v[7]);
        }
    } else {
        uint4 o;
        if (isb) {
            o.x = pack_bf16(f[0], f[1]);
            o.y = pack_bf16(f[2], f[3]);
            o.z = pack_bf16(f[4], f[5]);
            o.w = pack_bf16(f[6], f[7]);
        } else {
            __half2 ha = __floats2half2_rn(f[0], f[1]);
            __half2 hb = __floats2half2_rn(f[2], f[3]);
            __half2 hc = __floats2half2_rn(f[4], f[5]);
            __half2 hd = __floats2half2_rn(f[6], f[7]);
            o.x = *reinterpret_cast<unsigned int*>(&ha);
            o.y = *reinterpret_cast<unsigned int*>(&hb);
            o.z = *reinterpret_cast<unsigned int*>(&hc);
            o.w = *reinterpret_cast<unsigned int*>(&hd);
        }
        ((uint4*)next)[o16] = o;
    }
}

// ---------- R3 atomic fallback ----------

__global__ void init_kernel(const void* __restrict__ users,
                            const void* __restrict__ items,
                            void* __restrict__ out,
                            float* __restrict__ A,
                            float* __restrict__ B,
                            float* __restrict__ ACC,
                            const int* __restrict__ flag)
{
    int gid = blockIdx.x * blockDim.x + threadIdx.x;
    if (gid >= NODE_ELEMS) return;
    const bool isb = ((*flag) & 1);
    float v;
    if (gid < U_ELEMS) {
        if (isb) { bf16 b = ((const bf16*)users)[gid]; v = __bfloat162float(b); ((bf16*)out)[U_ELEMS + gid] = b; }
        else     { float fv = ((const float*)users)[gid]; v = fv; ((float*)out)[U_ELEMS + gid] = fv; }
    } else {
        int ii = gid - U_ELEMS;
        if (isb) { bf16 b = ((const bf16*)items)[ii]; v = __bfloat162float(b); ((bf16*)out)[2 * U_ELEMS + I_ELEMS + ii] = b; }
        else     { float fv = ((const float*)items)[ii]; v = fv; ((float*)out)[2 * U_ELEMS + I_ELEMS + ii] = fv; }
    }
    A[gid]   = v;
    B[gid]   = 0.0f;
    ACC[gid] = v;
}

__global__ void finalize_kernel(const float* __restrict__ acc,
                                void* __restrict__ out,
                                const int* __restrict__ flag)
{
    int gid = blockIdx.x * blockDim.x + threadIdx.x;
    if (gid >= NODE_ELEMS) return;
    const bool isb = ((*flag) & 1);
    float v = acc[gid] * 0.25f;
    size_t o = (gid < U_ELEMS) ? (size_t)gid : (size_t)(2 * U_ELEMS + (gid - U_ELEMS));
    if (isb) ((bf16*)out)[o]  = __float2bfloat16(v);
    else     ((float*)out)[o] = v;
}

__global__ void scatter_kernel(const int* __restrict__ ei32,
                               const void* __restrict__ ew,
                               const float* __restrict__ prev,
                               float* __restrict__ next,
                               const int* __restrict__ flag)
{
    int gid = blockIdx.x * blockDim.x + threadIdx.x;
    if (gid >= N_EDGES * 16) return;
    const int f = *flag;
    int e = gid >> 4;
    int j = (gid & 15) << 2;
    int row = load_row(ei32, f, e);
    int col = load_col(ei32, f, e);
    float w = load_w(ew, f, e);
    const float4 v = *reinterpret_cast<const float4*>(prev + (size_t)col * EMB + j);
    float* dst = next + (size_t)row * EMB + j;
    unsafeAtomicAdd(dst + 0, w * v.x);
    unsafeAtomicAdd(dst + 1, w * v.y);
    unsafeAtomicAdd(dst + 2, w * v.z);
    unsafeAtomicAdd(dst + 3, w * v.w);
}

__global__ void accum_zero_kernel(float* __restrict__ acc,
                                  const float* __restrict__ next,
                                  float* __restrict__ prevz)
{
    int gid = blockIdx.x * blockDim.x + threadIdx.x;
    if (gid >= NODE_ELEMS) return;
    acc[gid] += next[gid];
    prevz[gid] = 0.0f;
}

__global__ void sentinel_kernel(unsigned int* __restrict__ out, int nwords)
{
    int gid = blockIdx.x * blockDim.x + threadIdx.x;
    if (gid < nwords) out[gid] = 0x447A447Au;
}

extern "C" void kernel_launch(void* const* d_in, const int* in_sizes, int n_in,
                              void* d_out, int out_size, void* d_ws, size_t ws_size,
                              hipStream_t stream)
{
    const void* users = d_in[0];
    const void* items = d_in[1];
    const int*  ei32  = (const int*)d_in[2];
    const void* ew    = d_in[3];

    char* wsb  = (char*)d_ws;
    int*  flag = (int*)wsb;
    float* A   = (float*)(wsb + 256);              // fp32-sized; holds 16-bit in CSR path
    float* B   = A + (size_t)NODE_ELEMS;           // h1 buffer; aliases rec
    float* ACC = B + (size_t)NODE_ELEMS;           // h2 buffer; rec extends here
    char* p    = (char*)(ACC + (size_t)NODE_ELEMS);
    int*  rowptr      = (int*)p;  p += (N_NODES + 4) * sizeof(int);
    int*  bucket_cnt  = (int*)p;  p += (NB + 2) * sizeof(int);   // (unused, kept for layout)
    int*  bucket_base = (int*)p;  p += (NB + 2) * sizeof(int);   // (unused, kept for layout)
    int*  bucket_off  = (int*)p;  p += (NB + 2) * sizeof(int);
    int2* csr         = (int2*)p; p += (size_t)N_EDGES * sizeof(int2);  // packed (col,w)
    int2* rec         = (int2*)B;  // fixed-cap: NB*CAP int2 = 43.2MB, fits in B+ACC (76.8MB)

    const size_t need_csr    = (size_t)(p - wsb);                  // ~154.4 MB
    const size_t need_atomic = 256 + 3 * (size_t)NODE_ELEMS * sizeof(float);
    const int BLK = 256;
    const int node_blocks = (NODE_ELEMS + BLK - 1) / BLK;
    const int vec_blocks  = (NODE_ELEMS / 4 + BLK - 1) / BLK;
    const int row_blocks  = (N_NODES + 3) / 4;       // 4 rows (waves) per block
    const int bin_blocks  = (N_EDGES + EPB - 1) / EPB;   // 1172

    (void)bucket_cnt; (void)bucket_base;

    if (ws_size >= need_csr) {
        float* C = ACC;   // h2 buffer
        detect_kernel<<<1, BLK, 0, stream>>>((const unsigned short*)users, ei32, flag, bucket_off);
        init_vec_kernel<<<vec_blocks, BLK, 0, stream>>>(users, items, d_out, A, flag);
        bin_kernel<<<bin_blocks, 1024, 0, stream>>>(ei32, ew, bucket_off, rec, flag);
        local_fill_kernel<<<NB, 1024, 0, stream>>>(bucket_off, rec, csr, rowptr);

        // hop1: A(emb0) -> B(h1); hop2: B -> C(h2); hop3: C -> out, fusing
        // out = (A + B + C + h3)/4 in the epilogue.
        hop_kernel<false><<<row_blocks, BLK, 0, stream>>>(rowptr, csr, A, B, nullptr, nullptr, nullptr, flag);
        hop_kernel<false><<<row_blocks, BLK, 0, stream>>>(rowptr, csr, B, C, nullptr, nullptr, nullptr, flag);
        hop_kernel<true ><<<row_blocks, BLK, 0, stream>>>(rowptr, csr, C, nullptr, A, B, d_out, flag);
    } else if (ws_size >= need_atomic) {
        const int sedge_blocks = (N_EDGES * 16 + BLK - 1) / BLK;
        detect_kernel<<<1, BLK, 0, stream>>>((const unsigned short*)users, ei32, flag, bucket_off);
        init_kernel<<<node_blocks, BLK, 0, stream>>>(users, items, d_out, A, B, ACC, flag);
        float* prev = A;
        float* nxt  = B;
        for (int h = 0; h < 3; ++h) {
            scatter_kernel<<<sedge_blocks, BLK, 0, stream>>>(ei32, ew, prev, nxt, flag);
            accum_zero_kernel<<<node_blocks, BLK, 0, stream>>>(ACC, nxt, prev);
            float* t = prev; prev = nxt; nxt = t;
        }
        finalize_kernel<<<node_blocks, BLK, 0, stream>>>(ACC, d_out, flag);
    } else {
        int nwords = out_size / 2;
        sentinel_kernel<<<(nwords + BLK - 1) / BLK, BLK, 0, stream>>>((unsigned int*)d_out, nwords);
    }
}

// Round 17
// 482.748 us; speedup vs baseline: 1.0210x; 1.0210x over previous
//
#include <hip/hip_runtime.h>
#include <hip/hip_bf16.h>
#include <hip/hip_fp16.h>

// LightGCN 3-hop propagation, 150k nodes, 4.8M edges, EMB=64.
// Round 22 (session R16): RESUBMIT best-measured config (483.2us; passed
// R12/R13/R14/R15). R16's post-timing divergence (0.93 absmax after graph
// replays, identical source) is unreproducible from the code: every buffer
// read is written earlier in the same launch; atomic-order nondeterminism
// bounds at ~1e-5. Cold-container harness flake suspected. If it recurs,
// next step de-aliases rec from B/ACC.
// Config: fixed-cap bucket CSR build (detect-init offsets, bin LDS sort,
// 1024-thr local_fill w/ in-block base reduce), uint4 hop gathers w/
// depth-2 pipeline + predicated tail + pk_fma, fp16 internal storage,
// fused epilogue. Plateau: hops 3x94us = 298MB random L3 fetches/hop.

#define NUM_USERS 100000
#define NUM_ITEMS 50000
#define N_NODES   150000
#define EMB       64
#define N_EDGES   4800000
#define NODE_ELEMS (N_NODES * EMB)   // 9,600,000
#define U_ELEMS    (NUM_USERS * EMB) // 6,400,000
#define I_ELEMS    (NUM_ITEMS * EMB) // 3,200,000

#define RPB 256                       // rows per bucket (2^8: row>>8, row&255)
#define NB  ((N_NODES + RPB - 1) / RPB)   // 586 buckets
#define CAP 9216                      // bucket capacity (mean 8192, sigma~90)
#define EPB 4096                      // edges staged per bin block
#define EPW (EPB / 1024)              // edges per thread in bin_kernel

typedef __hip_bfloat16 bf16;
typedef float v2f __attribute__((ext_vector_type(2)));

__device__ __forceinline__ unsigned int pack_bf16(float a, float b) {
    bf16 x = __float2bfloat16(a), y = __float2bfloat16(b);
    return ((unsigned int)(*reinterpret_cast<unsigned short*>(&y)) << 16) |
           (*reinterpret_cast<unsigned short*>(&x));
}
__device__ __forceinline__ float bf_lo(unsigned int u) { return __uint_as_float(u << 16); }
__device__ __forceinline__ float bf_hi(unsigned int u) { return __uint_as_float(u & 0xffff0000u); }
__device__ __forceinline__ float2 h2f(unsigned int u) {
    return __half22float2(*reinterpret_cast<const __half2*>(&u));
}

// flag bit0: float arrays are bf16 (else fp32). bit1: edge_index int64 (else int32).
__global__ void detect_kernel(const unsigned short* __restrict__ u16,
                              const int* __restrict__ ei32,
                              int* __restrict__ flag,
                              int* __restrict__ bucket_off)
{
    __shared__ int s_fp32, s_i32;
    if (threadIdx.x == 0) { s_fp32 = 0; s_i32 = 0; }
    __syncthreads();
    int t = threadIdx.x;
    for (int i = t; i < NB + 1; i += 256) bucket_off[i] = i * CAP;
    unsigned short u = u16[t];
    int e = (u >> 7) & 0xFF;
    if (e >= 0xC0) atomicOr(&s_fp32, 1);
    if (t < 64 && ei32[2 * t + 1] != 0) atomicOr(&s_i32, 1);
    __syncthreads();
    if (t == 0) {
        int f = 0;
        if (!s_fp32) f |= 1;
        if (!s_i32)  f |= 2;
        *flag = f;
    }
}

__device__ __forceinline__ int load_row(const int* ei32, int f, size_t e) {
    return (f & 2) ? ei32[2 * e] : ei32[e];
}
__device__ __forceinline__ int load_col(const int* ei32, int f, size_t e) {
    return (f & 2) ? ei32[2 * ((size_t)N_EDGES + e)] : ei32[(size_t)N_EDGES + e];
}
__device__ __forceinline__ float load_w(const void* ew, int f, size_t e) {
    return (f & 1) ? __bfloat162float(((const bf16*)ew)[e]) : ((const float*)ew)[e];
}

// ---------- vectorized init: A (16-bit packed) + passthrough ----------
__global__ void init_vec_kernel(const void* __restrict__ users,
                                const void* __restrict__ items,
                                void* __restrict__ out,
                                void* __restrict__ A,
                                const int* __restrict__ flag)
{
    int g = blockIdx.x * blockDim.x + threadIdx.x;   // NODE_ELEMS/4 threads
    if (g >= NODE_ELEMS / 4) return;
    int g4 = g * 4;
    const bool isb = ((*flag) & 1);
    if (isb) {
        uint2 v;
        if (g4 < U_ELEMS) {
            v = ((const uint2*)users)[g];
            ((uint2*)((bf16*)out + U_ELEMS))[g] = v;
        } else {
            int ii = g - U_ELEMS / 4;
            v = ((const uint2*)items)[ii];
            ((uint2*)((bf16*)out + 2 * (size_t)U_ELEMS + I_ELEMS))[ii] = v;
        }
        ((uint2*)A)[g] = v;            // A stored bf16
    } else {
        float4 v;
        if (g4 < U_ELEMS) {
            v = ((const float4*)users)[g];
            ((float4*)((float*)out + U_ELEMS))[g] = v;
        } else {
            int ii = g - U_ELEMS / 4;
            v = ((const float4*)items)[ii];
            ((float4*)((float*)out + 2 * (size_t)U_ELEMS + I_ELEMS))[ii] = v;
        }
        __half2 ha = __floats2half2_rn(v.x, v.y);
        __half2 hb = __floats2half2_rn(v.z, v.w);
        uint2 u2;
        u2.x = *reinterpret_cast<unsigned int*>(&ha);
        u2.y = *reinterpret_cast<unsigned int*>(&hb);
        ((uint2*)A)[g] = u2;           // A stored fp16 (intermediates 16-bit)
    }
}

// ---------- binned CSR build (fixed-capacity buckets) ----------

// stage EPB edges in LDS, rank by bucket, append bucket-contiguous runs
// into fixed-capacity rec regions [b*CAP, (b+1)*CAP).
__global__ __launch_bounds__(1024) void bin_kernel(const int* __restrict__ ei32,
                                                   const void* __restrict__ ew,
                                                   int* __restrict__ bucket_off,
                                                   int2* __restrict__ rec,
                                                   const int* __restrict__ flag)
{
    __shared__ int2 stage[EPB];            // 32 KB
    __shared__ unsigned short bof[EPB];    // 8 KB
    __shared__ int hist[NB], excl0[NB], rank_[NB], gbase[NB];
    __shared__ int ls[16];
    const int t = threadIdx.x;
    const size_t base_e = (size_t)blockIdx.x * EPB;
    const int cnt = (int)(((base_e + EPB) <= N_EDGES) ? EPB : (N_EDGES - base_e));
    for (int i = t; i < NB; i += 1024) hist[i] = 0;
    __syncthreads();
    const int f = *flag;
    int  mybkt[EPW];
    int2 myrec[EPW];
    #pragma unroll
    for (int k = 0; k < EPW; ++k) {
        int idx = k * 1024 + t;
        if (idx < cnt) {
            size_t e = base_e + idx;
            int row, col;
            if (f & 2) {   // int64 input: int2 vector load, keep low word
                row = ((const int2*)ei32)[e].x;
                col = ((const int2*)ei32)[(size_t)N_EDGES + e].x;
            } else {
                row = ei32[e];
                col = ei32[(size_t)N_EDGES + e];
            }
            float w = load_w(ew, f, e);
            mybkt[k] = row >> 8;
            myrec[k] = make_int2(col | ((row & 255) << 18), __float_as_int(w));
            atomicAdd(&hist[mybkt[k]], 1);
        } else mybkt[k] = -1;
    }
    __syncthreads();
    {   // scan hist[0..NB) -> excl0, rank_
        const int lane = t & 63, wv = t >> 6;
        int x = (t < NB) ? hist[t] : 0;
        int v = x;
        #pragma unroll
        for (int d = 1; d < 64; d <<= 1) { int y = __shfl_up(v, d, 64); if (lane >= d) v += y; }
        if (lane == 63) ls[wv] = v;
        __syncthreads();
        if (wv == 0 && lane < 16) {
            int s = ls[lane];
            #pragma unroll
            for (int d = 1; d < 16; d <<= 1) { int y = __shfl_up(s, d, 64); if (lane >= d) s += y; }
            ls[lane] = s;
        }
        __syncthreads();
        int waveoff = wv ? ls[wv - 1] : 0;
        int excl = waveoff + v - x;
        if (t < NB) { excl0[t] = excl; rank_[t] = excl; }
    }
    __syncthreads();
    if (t < NB && hist[t] > 0) gbase[t] = atomicAdd(&bucket_off[t], hist[t]);
    else if (t < NB)           gbase[t] = 0;
    #pragma unroll
    for (int k = 0; k < EPW; ++k) {
        if (mybkt[k] >= 0) {
            int p = atomicAdd(&rank_[mybkt[k]], 1);
            stage[p] = myrec[k];
            bof[p]   = (unsigned short)mybkt[k];
        }
    }
    __syncthreads();
    for (int s = t; s < cnt; s += 1024) {
        int b = bof[s];
        int pos = gbase[b] + (s - excl0[b]);
        if (pos < (b + 1) * CAP)           // overflow clamp (11-sigma margin)
            rec[pos] = stage[s];
    }
}

// one 1024-thread block per bucket: compute dense base from bucket_off
// (no global scan kernel), local row hist + scan -> rowptr, scatter
// packed (col,w) csr from the bucket's fixed-cap rec region.
__global__ __launch_bounds__(1024) void local_fill_kernel(
                                  const int* __restrict__ bucket_off,
                                  const int2* __restrict__ rec,
                                  int2* __restrict__ csr,
                                  int* __restrict__ rowptr)
{
    __shared__ int hist[RPB], off[RPB], ls[4], s_red[16], s_dlo;
    const int b = blockIdx.x, t = threadIdx.x;      // 1024 threads
    const int src = b * CAP;
    int cnt = bucket_off[b] - src;
    if (cnt > CAP) cnt = CAP;
    const int rows = (N_NODES - b * RPB < RPB) ? (N_NODES - b * RPB) : RPB;
    const int lane = t & 63, wv = t >> 6;

    // exclusive sum of bucket counts for i < b (dense csr base)
    int partial = 0;
    for (int i = t; i < b; i += 1024) {
        int c = bucket_off[i] - i * CAP;
        if (c > CAP) c = CAP;
        partial += c;
    }
    #pragma unroll
    for (int d = 1; d < 64; d <<= 1) partial += __shfl_xor(partial, d, 64);
    if (lane == 0) s_red[wv] = partial;
    if (t < RPB) hist[t] = 0;
    __syncthreads();
    if (t == 0) {
        int s = 0;
        #pragma unroll
        for (int i = 0; i < 16; ++i) s += s_red[i];
        s_dlo = s;
    }
    for (int s = t; s < cnt; s += 1024)
        atomicAdd(&hist[rec[src + s].x >> 18], 1);
    __syncthreads();
    const int dlo = s_dlo;
    int x = (t < RPB) ? hist[t] : 0;
    int v = x;
    #pragma unroll
    for (int d = 1; d < 64; d <<= 1) { int y = __shfl_up(v, d, 64); if (lane >= d) v += y; }
    if (t < RPB && lane == 63) ls[wv] = v;
    __syncthreads();
    if (wv == 0 && lane < 4) {
        int s = ls[lane];
        #pragma unroll
        for (int d = 1; d < 4; d <<= 1) { int y = __shfl_up(s, d, 64); if (lane >= d) s += y; }
        ls[lane] = s;
    }
    __syncthreads();
    if (t < RPB) {
        int waveoff = wv ? ls[wv - 1] : 0;
        int excl = waveoff + v - x;
        if (t < rows) rowptr[b * RPB + t] = dlo + excl;
        off[t] = dlo + excl;
    }
    if (b == NB - 1 && t == 0) rowptr[N_NODES] = dlo + cnt;
    __syncthreads();
    for (int s = t; s < cnt; s += 1024) {
        int2 r = rec[src + s];
        int rl = r.x >> 18;
        int pos = atomicAdd(&off[rl], 1);
        csr[pos] = make_int2(r.x & 0x3FFFF, r.y);   // packed (col, w-bits)
    }
}

// ---------- gather hop core: uint4 gathers, packed-fp32 FMA ----------
// Lane q=(tid>>3)&7 owns edge-slot q of each 8-edge step; hl=tid&7 owns
// dims {8hl..8hl+7} as one uint4 (8 x 16-bit). 16-edge chunk = 2 steps.
// Accumulate in 4x float2 via __builtin_elementwise_fma -> v_pk_fma_f32.
// Main loop: depth-2 pipeline. Tail: ONE predicated 16-slot step.

template <bool ISB>
__device__ __forceinline__ void gather_row8(const int2* __restrict__ csr,
                                            const uint4* __restrict__ p,
                                            int s, int e, int q, int hl,
                                            float f[8])
{
    const int len   = e - s;
    const int nfull = len >> 4;          // full 16-edge chunks
    const int rem   = len & 15;

    v2f a01 = {0.f, 0.f}, a23 = {0.f, 0.f}, a45 = {0.f, 0.f}, a67 = {0.f, 0.f};

    int2 cwA[2], cwB[2];
    uint4 vA[2], vB[2];

#define LD_CSR(cw, base)                                             \
    _Pragma("unroll")                                                \
    for (int u = 0; u < 2; ++u) (cw)[u] = csr[(base) + 8 * u + q];
#define GATHER(v, cw)                                                \
    _Pragma("unroll")                                                \
    for (int u = 0; u < 2; ++u)                                      \
        (v)[u] = p[(size_t)((unsigned int)(cw)[u].x * 8u + hl)];
#define FMA2(cw, v)                                                  \
    _Pragma("unroll")                                                \
    for (int u = 0; u < 2; ++u) {                                    \
        float w = __int_as_float((cw)[u].y);                         \
        v2f wv = {w, w};                                             \
        v2f p01, p23, p45, p67;                                      \
        if (ISB) {                                                   \
            p01 = (v2f){bf_lo((v)[u].x), bf_hi((v)[u].x)};           \
            p23 = (v2f){bf_lo((v)[u].y), bf_hi((v)[u].y)};           \
            p45 = (v2f){bf_lo((v)[u].z), bf_hi((v)[u].z)};           \
            p67 = (v2f){bf_lo((v)[u].w), bf_hi((v)[u].w)};           \
        } else {                                                     \
            float2 fa = h2f((v)[u].x), fb = h2f((v)[u].y);           \
            float2 fc = h2f((v)[u].z), fd = h2f((v)[u].w);           \
            p01 = (v2f){fa.x, fa.y}; p23 = (v2f){fb.x, fb.y};        \
            p45 = (v2f){fc.x, fc.y}; p67 = (v2f){fd.x, fd.y};        \
        }                                                            \
        a01 = __builtin_elementwise_fma(wv, p01, a01);               \
        a23 = __builtin_elementwise_fma(wv, p23, a23);               \
        a45 = __builtin_elementwise_fma(wv, p45, a45);               \
        a67 = __builtin_elementwise_fma(wv, p67, a67);               \
    }

    if (nfull > 0) {
        LD_CSR(cwA, s);
        if (nfull > 1) LD_CSR(cwB, s + 16);
        GATHER(vA, cwA);
        int c = 0;
        while (true) {
            // chunk c in A, chunk c+1 in B
            if (c + 1 < nfull) GATHER(vB, cwB);
            FMA2(cwA, vA);
            if (c + 1 >= nfull) break;
            if (c + 2 < nfull) LD_CSR(cwA, s + (c + 2) * 16);
            ++c;
            // chunk c in B, chunk c+1 in A
            if (c + 1 < nfull) GATHER(vA, cwA);
            FMA2(cwB, vB);
            if (c + 1 >= nfull) break;
            if (c + 2 < nfull) LD_CSR(cwB, s + (c + 2) * 16);
            ++c;
        }
    }
    if (rem) {
        const int base = s + nfull * 16;
        int2 cw[2];
        #pragma unroll
        for (int u = 0; u < 2; ++u) {
            int idx = base + 8 * u + q;
            int j = (idx < e) ? idx : (e - 1);
            cw[u] = csr[j];
            if (idx >= e) cw[u].y = 0;     // w = 0 for padding slots
        }
        uint4 v[2];
        #pragma unroll
        for (int u = 0; u < 2; ++u)
            v[u] = p[(size_t)((unsigned int)cw[u].x * 8u + hl)];
        FMA2(cw, v);
    }
#undef LD_CSR
#undef GATHER
#undef FMA2
    f[0] = a01.x; f[1] = a01.y; f[2] = a23.x; f[3] = a23.y;
    f[4] = a45.x; f[5] = a45.y; f[6] = a67.x; f[7] = a67.y;
}

// LAST fuses epilogue: out = (emb0 + h1 + h2 + h3)/4.
template <bool LAST>
__global__ void hop_kernel(const int* __restrict__ rowptr,
                           const int2* __restrict__ csr,
                           const void* __restrict__ prev,
                           void* __restrict__ next,
                           const void* __restrict__ E0,   // emb0 (LAST only)
                           const void* __restrict__ H1,   // h1   (LAST only)
                           void* __restrict__ out,
                           const int* __restrict__ flag)
{
    int row = blockIdx.x * (blockDim.x >> 6) + (threadIdx.x >> 6);
    if (row >= N_NODES) return;
    const int q  = (threadIdx.x >> 3) & 7;
    const int hl = threadIdx.x & 7;
    const bool isb = ((*flag) & 1);
    const int s = rowptr[row], e = rowptr[row + 1];
    const uint4* p = (const uint4*)prev;
    float f[8] = {0.f, 0.f, 0.f, 0.f, 0.f, 0.f, 0.f, 0.f};
    if (isb) gather_row8<true >(csr, p, s, e, q, hl, f);
    else     gather_row8<false>(csr, p, s, e, q, hl, f);
    #pragma unroll
    for (int k = 0; k < 8; ++k) {        // combine the 8 edge-slot groups
        f[k] += __shfl_xor(f[k], 8);
        f[k] += __shfl_xor(f[k], 16);
        f[k] += __shfl_xor(f[k], 32);
    }
    if ((threadIdx.x & 56) != 0) return; // slot-0 lanes (8 per row) write
    size_t o16 = (size_t)row * 8 + hl;   // 8-element (16-byte) units
    if (LAST) {
        uint4 e0u = ((const uint4*)E0)[o16];
        uint4 h1u = ((const uint4*)H1)[o16];
        uint4 h2u = ((const uint4*)prev)[o16];
        float v[8];
        if (isb) {
            v[0] = (bf_lo(e0u.x) + bf_lo(h1u.x) + bf_lo(h2u.x) + f[0]) * 0.25f;
            v[1] = (bf_hi(e0u.x) + bf_hi(h1u.x) + bf_hi(h2u.x) + f[1]) * 0.25f;
            v[2] = (bf_lo(e0u.y) + bf_lo(h1u.y) + bf_lo(h2u.y) + f[2]) * 0.25f;
            v[3] = (bf_hi(e0u.y) + bf_hi(h1u.y) + bf_hi(h2u.y) + f[3]) * 0.25f;
            v[4] = (bf_lo(e0u.z) + bf_lo(h1u.z) + bf_lo(h2u.z) + f[4]) * 0.25f;
            v[5] = (bf_hi(e0u.z) + bf_hi(h1u.z) + bf_hi(h2u.z) + f[5]) * 0.25f;
            v[6] = (bf_lo(e0u.w) + bf_lo(h1u.w) + bf_lo(h2u.w) + f[6]) * 0.25f;
            v[7] = (bf_hi(e0u.w) + bf_hi(h1u.w) + bf_hi(h2u.w) + f[7]) * 0.25f;
            uint4 o;
            o.x = pack_bf16(v[0], v[1]);
            o.y = pack_bf16(v[2], v[3]);
            o.z = pack_bf16(v[4], v[5]);
            o.w = pack_bf16(v[6], v[7]);
            size_t oo = o16 + ((row < NUM_USERS) ? 0 : (size_t)(U_ELEMS / 8));
            ((uint4*)out)[oo] = o;
        } else {
            float2 a0 = h2f(e0u.x), a1 = h2f(e0u.y), a2 = h2f(e0u.z), a3 = h2f(e0u.w);
            float2 b0 = h2f(h1u.x), b1 = h2f(h1u.y), b2 = h2f(h1u.z), b3 = h2f(h1u.w);
            float2 c0 = h2f(h2u.x), c1 = h2f(h2u.y), c2 = h2f(h2u.z), c3 = h2f(h2u.w);
            v[0] = (a0.x + b0.x + c0.x + f[0]) * 0.25f;
            v[1] = (a0.y + b0.y + c0.y + f[1]) * 0.25f;
            v[2] = (a1.x + b1.x + c1.x + f[2]) * 0.25f;
            v[3] = (a1.y + b1.y + c1.y + f[3]) * 0.25f;
            v[4] = (a2.x + b2.x + c2.x + f[4]) * 0.25f;
            v[5] = (a2.y + b2.y + c2.y + f[5]) * 0.25f;
            v[6] = (a3.x + b3.x + c3.x + f[6]) * 0.25f;
            v[7] = (a3.y + b3.y + c3.y + f[7]) * 0.25f;
            size_t fo = (size_t)row * 64 + (size_t)hl * 8 +
                        ((row < NUM_USERS) ? 0 : (size_t)U_ELEMS);
            float4* op = (float4*)((float*)out + fo);
            op[0] = make_float4(v[0], v[1], v[2], v[3]);
            op[1] = make_float4(v[4], v[5], v[6], v[7]);
        }
    } else {
        uint4 o;
        if (isb) {
            o.x = pack_bf16(f[0], f[1]);
            o.y = pack_bf16(f[2], f[3]);
            o.z = pack_bf16(f[4], f[5]);
            o.w = pack_bf16(f[6], f[7]);
        } else {
            __half2 ha = __floats2half2_rn(f[0], f[1]);
            __half2 hb = __floats2half2_rn(f[2], f[3]);
            __half2 hc = __floats2half2_rn(f[4], f[5]);
            __half2 hd = __floats2half2_rn(f[6], f[7]);
            o.x = *reinterpret_cast<unsigned int*>(&ha);
            o.y = *reinterpret_cast<unsigned int*>(&hb);
            o.z = *reinterpret_cast<unsigned int*>(&hc);
            o.w = *reinterpret_cast<unsigned int*>(&hd);
        }
        ((uint4*)next)[o16] = o;
    }
}

// ---------- R3 atomic fallback ----------

__global__ void init_kernel(const void* __restrict__ users,
                            const void* __restrict__ items,
                            void* __restrict__ out,
                            float* __restrict__ A,
                            float* __restrict__ B,
                            float* __restrict__ ACC,
                            const int* __restrict__ flag)
{
    int gid = blockIdx.x * blockDim.x + threadIdx.x;
    if (gid >= NODE_ELEMS) return;
    const bool isb = ((*flag) & 1);
    float v;
    if (gid < U_ELEMS) {
        if (isb) { bf16 b = ((const bf16*)users)[gid]; v = __bfloat162float(b); ((bf16*)out)[U_ELEMS + gid] = b; }
        else     { float fv = ((const float*)users)[gid]; v = fv; ((float*)out)[U_ELEMS + gid] = fv; }
    } else {
        int ii = gid - U_ELEMS;
        if (isb) { bf16 b = ((const bf16*)items)[ii]; v = __bfloat162float(b); ((bf16*)out)[2 * U_ELEMS + I_ELEMS + ii] = b; }
        else     { float fv = ((const float*)items)[ii]; v = fv; ((float*)out)[2 * U_ELEMS + I_ELEMS + ii] = fv; }
    }
    A[gid]   = v;
    B[gid]   = 0.0f;
    ACC[gid] = v;
}

__global__ void finalize_kernel(const float* __restrict__ acc,
                                void* __restrict__ out,
                                const int* __restrict__ flag)
{
    int gid = blockIdx.x * blockDim.x + threadIdx.x;
    if (gid >= NODE_ELEMS) return;
    const bool isb = ((*flag) & 1);
    float v = acc[gid] * 0.25f;
    size_t o = (gid < U_ELEMS) ? (size_t)gid : (size_t)(2 * U_ELEMS + (gid - U_ELEMS));
    if (isb) ((bf16*)out)[o]  = __float2bfloat16(v);
    else     ((float*)out)[o] = v;
}

__global__ void scatter_kernel(const int* __restrict__ ei32,
                               const void* __restrict__ ew,
                               const float* __restrict__ prev,
                               float* __restrict__ next,
                               const int* __restrict__ flag)
{
    int gid = blockIdx.x * blockDim.x + threadIdx.x;
    if (gid >= N_EDGES * 16) return;
    const int f = *flag;
    int e = gid >> 4;
    int j = (gid & 15) << 2;
    int row = load_row(ei32, f, e);
    int col = load_col(ei32, f, e);
    float w = load_w(ew, f, e);
    const float4 v = *reinterpret_cast<const float4*>(prev + (size_t)col * EMB + j);
    float* dst = next + (size_t)row * EMB + j;
    unsafeAtomicAdd(dst + 0, w * v.x);
    unsafeAtomicAdd(dst + 1, w * v.y);
    unsafeAtomicAdd(dst + 2, w * v.z);
    unsafeAtomicAdd(dst + 3, w * v.w);
}

__global__ void accum_zero_kernel(float* __restrict__ acc,
                                  const float* __restrict__ next,
                                  float* __restrict__ prevz)
{
    int gid = blockIdx.x * blockDim.x + threadIdx.x;
    if (gid >= NODE_ELEMS) return;
    acc[gid] += next[gid];
    prevz[gid] = 0.0f;
}

__global__ void sentinel_kernel(unsigned int* __restrict__ out, int nwords)
{
    int gid = blockIdx.x * blockDim.x + threadIdx.x;
    if (gid < nwords) out[gid] = 0x447A447Au;
}

extern "C" void kernel_launch(void* const* d_in, const int* in_sizes, int n_in,
                              void* d_out, int out_size, void* d_ws, size_t ws_size,
                              hipStream_t stream)
{
    const void* users = d_in[0];
    const void* items = d_in[1];
    const int*  ei32  = (const int*)d_in[2];
    const void* ew    = d_in[3];

    char* wsb  = (char*)d_ws;
    int*  flag = (int*)wsb;
    float* A   = (float*)(wsb + 256);              // fp32-sized; holds 16-bit in CSR path
    float* B   = A + (size_t)NODE_ELEMS;           // h1 buffer; aliases rec
    float* ACC = B + (size_t)NODE_ELEMS;           // h2 buffer; rec extends here
    char* p    = (char*)(ACC + (size_t)NODE_ELEMS);
    int*  rowptr      = (int*)p;  p += (N_NODES + 4) * sizeof(int);
    int*  bucket_cnt  = (int*)p;  p += (NB + 2) * sizeof(int);   // (unused, kept for layout)
    int*  bucket_base = (int*)p;  p += (NB + 2) * sizeof(int);   // (unused, kept for layout)
    int*  bucket_off  = (int*)p;  p += (NB + 2) * sizeof(int);
    int2* csr         = (int2*)p; p += (size_t)N_EDGES * sizeof(int2);  // packed (col,w)
    int2* rec         = (int2*)B;  // fixed-cap: NB*CAP int2 = 43.2MB, fits in B+ACC (76.8MB)

    const size_t need_csr    = (size_t)(p - wsb);                  // ~154.4 MB
    const size_t need_atomic = 256 + 3 * (size_t)NODE_ELEMS * sizeof(float);
    const int BLK = 256;
    const int node_blocks = (NODE_ELEMS + BLK - 1) / BLK;
    const int vec_blocks  = (NODE_ELEMS / 4 + BLK - 1) / BLK;
    const int row_blocks  = (N_NODES + 3) / 4;       // 4 rows (waves) per block
    const int bin_blocks  = (N_EDGES + EPB - 1) / EPB;   // 1172

    (void)bucket_cnt; (void)bucket_base;

    if (ws_size >= need_csr) {
        float* C = ACC;   // h2 buffer
        detect_kernel<<<1, BLK, 0, stream>>>((const unsigned short*)users, ei32, flag, bucket_off);
        init_vec_kernel<<<vec_blocks, BLK, 0, stream>>>(users, items, d_out, A, flag);
        bin_kernel<<<bin_blocks, 1024, 0, stream>>>(ei32, ew, bucket_off, rec, flag);
        local_fill_kernel<<<NB, 1024, 0, stream>>>(bucket_off, rec, csr, rowptr);

        // hop1: A(emb0) -> B(h1); hop2: B -> C(h2); hop3: C -> out, fusing
        // out = (A + B + C + h3)/4 in the epilogue.
        hop_kernel<false><<<row_blocks, BLK, 0, stream>>>(rowptr, csr, A, B, nullptr, nullptr, nullptr, flag);
        hop_kernel<false><<<row_blocks, BLK, 0, stream>>>(rowptr, csr, B, C, nullptr, nullptr, nullptr, flag);
        hop_kernel<true ><<<row_blocks, BLK, 0, stream>>>(rowptr, csr, C, nullptr, A, B, d_out, flag);
    } else if (ws_size >= need_atomic) {
        const int sedge_blocks = (N_EDGES * 16 + BLK - 1) / BLK;
        detect_kernel<<<1, BLK, 0, stream>>>((const unsigned short*)users, ei32, flag, bucket_off);
        init_kernel<<<node_blocks, BLK, 0, stream>>>(users, items, d_out, A, B, ACC, flag);
        float* prev = A;
        float* nxt  = B;
        for (int h = 0; h < 3; ++h) {
            scatter_kernel<<<sedge_blocks, BLK, 0, stream>>>(ei32, ew, prev, nxt, flag);
            accum_zero_kernel<<<node_blocks, BLK, 0, stream>>>(ACC, nxt, prev);
            float* t = prev; prev = nxt; nxt = t;
        }
        finalize_kernel<<<node_blocks, BLK, 0, stream>>>(ACC, d_out, flag);
    } else {
        int nwords = out_size / 2;
        sentinel_kernel<<<(nwords + BLK - 1) / BLK, BLK, 0, stream>>>((unsigned int*)d_out, nwords);
    }
}